// Round 20
// baseline (81.115 us; speedup 1.0000x reference)
//
#include <hip/hip_runtime.h>

#define BB 512
#define SS 512
#define TT 64
#define TSTRIDE 66   // transitions is (66,66)

typedef _Float16 h2 __attribute__((ext_vector_type(2)));
typedef int i2v __attribute__((ext_vector_type(2)));

static __device__ __forceinline__ float first_lane(float v) {
    return __int_as_float(__builtin_amdgcn_readfirstlane(__float_as_int(v)));
}
static __device__ __forceinline__ unsigned pk_f16(float a, float b) {
    return __builtin_bit_cast(unsigned, __builtin_amdgcn_cvt_pkrtz(a, b));
}
static __device__ __forceinline__ h2 as_h2(unsigned u) {
    return __builtin_bit_cast(h2, u);
}
static __device__ __forceinline__ unsigned bperm(int addr, unsigned v) {
    return (unsigned)__builtin_amdgcn_ds_bpermute(addr, (int)v);
}
static __device__ __forceinline__ float swz16f(float v) {   // value from lane^16
    return __int_as_float(__builtin_amdgcn_ds_swizzle(__float_as_int(v), 0x401F));
}
#define FDOT2(a, b, c) __builtin_amdgcn_fdot2((a), (b), (c), false)
#define DPPF(v, ctrl) __int_as_float(__builtin_amdgcn_mov_dpp(__float_as_int(v), (ctrl), 0xF, 0xF, true))
#define DPPU(v, ctrl) ((unsigned)__builtin_amdgcn_mov_dpp((int)(v), (ctrl), 0xF, 0xF, true))

#define DO32(F) F(0) F(1) F(2) F(3) F(4) F(5) F(6) F(7) \
                F(8) F(9) F(10) F(11) F(12) F(13) F(14) F(15) \
                F(16) F(17) F(18) F(19) F(20) F(21) F(22) F(23) \
                F(24) F(25) F(26) F(27) F(28) F(29) F(30) F(31)

// R20 = R19 (rank-1 4-segment MITM, waves_per_eu(3,3)) + ONE memory clobber
// after the E-table hoist. R17/R19 showed the compiler REMATERIALIZES the
// EQ[w][j] loads each step whenever max-waves > 1 (legal: LDS unchanged),
// evicting E (VGPR 68) and making every step pay LDS re-read latency.
// The clobber makes re-loading non-provably-equal -> the 32 values MUST
// stay live in VGPRs. Budget at (3,3) = 512/3 ~= 170 >= ~132 needed, and
// HW grants 3 waves/SIMD at 132 VGPR (396 <= 512). First config with all
// three: depth 128 x E-resident pure-VALU step x 3-way co-residency.
// Segments: A = steps 1..127 exact from v0; B = 128..255, C = 256..383
// rank-1 compressed (Birkhoff contraction => exact in f32); D = 511..384
// exact from stop. logZ = LSE(d+Cu)+LSE(CTu+Bu)+LSE(BTu+a)-LSE(Cu)-LSE(Bu).
// Step = R15 skeleton: product-form recurrence, blocked dots
// (tl={0,2,7,5,15,13,8,10}), VALU reduce (perm16+perm32).
// roles: 0=a(fwd,v0) 1=Bu(fwd,u) 3=Cu(fwd,u) | 2=BTu(bwd,u) 4=CTu(bwd,u)
//        5=d(bwd,stop)
__global__ __launch_bounds__(64)
__attribute__((amdgpu_waves_per_eu(3, 3)))
void crf_scan6_kernel(
    const float* __restrict__ emissions,   // [B,S,T]
    const float* __restrict__ mask,        // [B,S]
    const float* __restrict__ trans,       // [66,66]
    float* __restrict__ ws_state)          // [B][6][64] log-form vectors
{
    __shared__ unsigned EQ[32][64];        // 8 KB E-fragment staging

    const int blk  = blockIdx.x;
    const int b    = blk / 6;
    const int role = blk - 6 * b;
    const bool isFwd = (role == 0) | (role == 1) | (role == 3);
    const int j   = threadIdx.x;   // 0..63
    const bool lo32  = (j < 32);
    const bool odd16 = (j & 16) != 0;
    const int a32v = ((j ^ 32) << 2);      // bpermute fallback address

    const float* em = emissions + (size_t)b * SS * TT;
    const float* mk = mask + (size_t)b * SS;

    // ---- E fragments, pre-permuted (R11-verified layout) ----
    {
        const int tl[8] = {0, 2, 7, 5, 15, 13, 8, 10};
        #pragma unroll
        for (int w = 0; w < 32; ++w) {
            int m = w >> 3, k = w & 7;
            int y0 = j ^ tl[k];
            int y1 = y0 ^ 1;
            int x  = j ^ (m << 4);
            if (isFwd)      // fwd: M[x][y] = trans[y*66 + x]
                EQ[w][j] = pk_f16(__expf(trans[y0 * TSTRIDE + x]),
                                  __expf(trans[y1 * TSTRIDE + x]));
            else            // bwd: M[x][y] = trans[x*66 + y]
                EQ[w][j] = pk_f16(__expf(trans[x * TSTRIDE + y0]),
                                  __expf(trans[x * TSTRIDE + y1]));
        }
    }
    __syncthreads();

#define CDECL(K) unsigned c##K = EQ[K][j];
    DO32(CDECL)
#undef CDECL
    // Kill rematerialization: after this clobber the compiler cannot prove a
    // re-read of EQ returns the same bytes, so c0..c31 must stay in VGPRs.
    asm volatile("" ::: "memory");

#if defined(__has_builtin) && __has_builtin(__builtin_amdgcn_permlane32_swap)
#define XCH32F(DST, SRC) { i2v r_ = __builtin_amdgcn_permlane32_swap( \
                               __float_as_int(SRC), __float_as_int(SRC), false, false); \
                           DST = __int_as_float(lo32 ? r_.y : r_.x); }
#else
#define XCH32F(DST, SRC) { DST = __int_as_float((int)bperm(a32v, (unsigned)__float_as_int(SRC))); }
#endif

#if defined(__has_builtin) && __has_builtin(__builtin_amdgcn_permlane16_swap)
#define XCH16F(DST, SRC) { i2v r_ = __builtin_amdgcn_permlane16_swap( \
                               __float_as_int(SRC), __float_as_int(SRC), false, false); \
                           DST = __int_as_float(odd16 ? r_.x : r_.y); }
#else
#define XCH16F(DST, SRC) { DST = swz16f(SRC); }
#endif

    // len (len in [256,512]; masked GPREP is a no-op for always-valid ranges)
    float msum = 0.f;
    #pragma unroll
    for (int tq = 0; tq < 8; ++tq) msum += mk[j + 64 * tq];
    #pragma unroll
    for (int off = 32; off; off >>= 1) msum += __shfl_xor(msum, off);
    const int len = (int)(first_lane(msum) + 0.5f);

    float t, L2 = 0.f, Lc = 0.f;

#define STEPP(GK) do { \
        float pn_ = DPPF(t, 0xB1); \
        unsigned W0 = pk_f16(t, pn_); \
        unsigned W1 = DPPU(W0, 0x4E); \
        unsigned W2 = DPPU(W0, 0x141); \
        unsigned W3 = DPPU(W1, 0x141); \
        unsigned W4 = DPPU(W0, 0x140); \
        unsigned W5 = DPPU(W1, 0x140); \
        unsigned W6 = DPPU(W4, 0x141); \
        unsigned W7 = DPPU(W5, 0x141); \
        float a0_ = 0.f, a1_ = 0.f, a2_ = 0.f, a3_ = 0.f; \
        a0_ = FDOT2(as_h2(W0), as_h2(c0),  a0_); \
        a1_ = FDOT2(as_h2(W0), as_h2(c8),  a1_); \
        a2_ = FDOT2(as_h2(W0), as_h2(c16), a2_); \
        a3_ = FDOT2(as_h2(W0), as_h2(c24), a3_); \
        a0_ = FDOT2(as_h2(W1), as_h2(c1),  a0_); \
        a1_ = FDOT2(as_h2(W1), as_h2(c9),  a1_); \
        a2_ = FDOT2(as_h2(W1), as_h2(c17), a2_); \
        a3_ = FDOT2(as_h2(W1), as_h2(c25), a3_); \
        a0_ = FDOT2(as_h2(W2), as_h2(c2),  a0_); \
        a1_ = FDOT2(as_h2(W2), as_h2(c10), a1_); \
        a2_ = FDOT2(as_h2(W2), as_h2(c18), a2_); \
        a3_ = FDOT2(as_h2(W2), as_h2(c26), a3_); \
        a0_ = FDOT2(as_h2(W3), as_h2(c3),  a0_); \
        a1_ = FDOT2(as_h2(W3), as_h2(c11), a1_); \
        a2_ = FDOT2(as_h2(W3), as_h2(c19), a2_); \
        a3_ = FDOT2(as_h2(W3), as_h2(c27), a3_); \
        a0_ = FDOT2(as_h2(W4), as_h2(c4),  a0_); \
        a1_ = FDOT2(as_h2(W4), as_h2(c12), a1_); \
        a2_ = FDOT2(as_h2(W4), as_h2(c20), a2_); \
        a3_ = FDOT2(as_h2(W4), as_h2(c28), a3_); \
        a0_ = FDOT2(as_h2(W5), as_h2(c5),  a0_); \
        a1_ = FDOT2(as_h2(W5), as_h2(c13), a1_); \
        a2_ = FDOT2(as_h2(W5), as_h2(c21), a2_); \
        a3_ = FDOT2(as_h2(W5), as_h2(c29), a3_); \
        a0_ = FDOT2(as_h2(W6), as_h2(c6),  a0_); \
        a1_ = FDOT2(as_h2(W6), as_h2(c14), a1_); \
        a2_ = FDOT2(as_h2(W6), as_h2(c22), a2_); \
        a3_ = FDOT2(as_h2(W6), as_h2(c30), a3_); \
        a0_ = FDOT2(as_h2(W7), as_h2(c7),  a0_); \
        a1_ = FDOT2(as_h2(W7), as_h2(c15), a1_); \
        a2_ = FDOT2(as_h2(W7), as_h2(c23), a2_); \
        a3_ = FDOT2(as_h2(W7), as_h2(c31), a3_); \
        float a1x_, a3x_; \
        XCH16F(a1x_, a1_) \
        XCH16F(a3x_, a3_) \
        float V0 = a0_ + a1x_; \
        float V1 = a2_ + a3x_; \
        float Vx; XCH32F(Vx, V1); \
        float sum_ = V0 + Vx; \
        float s0_ = first_lane(sum_); \
        L2 += __log2f(s0_); \
        t = (sum_ * (GK)) * __builtin_amdgcn_rcpf(s0_); \
    } while (0)

#define GPREPM(RK, SV, GOUT) { float ee_ = ((SV) < len) ? (RK) : 0.0f; \
                               float e0_ = first_lane(ee_); \
                               GOUT = __expf(ee_ - e0_ - 4.0f); Lc += e0_ + 4.0f; }

    const float LN2 = 0.69314718055994531f;
    float anchor;

    if (isFwd) {
        // roles 0/1/3: fwd, steps sBase..sBase+126(+127)
        const int sBase = (role == 0) ? 1 : ((role == 1) ? 128 : 256);
        if (role == 0) {
            float sc0 = em[j] + trans[j * TSTRIDE + TT];  // mask[0]==1 always
            anchor = first_lane(sc0) + 4.0f;
            t = __expf(sc0 - anchor);
        } else {
            anchor = 0.0f;
            t = 1.0f;                                     // uniform start
        }
        float r0 = em[(size_t)(sBase + 0) * TT + j], r1 = em[(size_t)(sBase + 1) * TT + j];
        float r2 = em[(size_t)(sBase + 2) * TT + j], r3 = em[(size_t)(sBase + 3) * TT + j];
        float r4 = em[(size_t)(sBase + 4) * TT + j], r5 = em[(size_t)(sBase + 5) * TT + j];
        float r6 = em[(size_t)(sBase + 6) * TT + j], r7 = em[(size_t)(sBase + 7) * TT + j];
        const float* pe = em + (size_t)(sBase + 8) * TT + j;
        int scur = sBase;
        for (int it = 0; it < 15; ++it) {       // 120 steps
            float n0 = pe[0],   n1 = pe[64],  n2 = pe[128], n3 = pe[192];
            float n4 = pe[256], n5 = pe[320], n6 = pe[384], n7 = pe[448];
            pe += 512;
            float g0, g1, g2, g3, g4, g5, g6, g7;
            GPREPM(r0, scur + 0, g0) GPREPM(r1, scur + 1, g1)
            GPREPM(r2, scur + 2, g2) GPREPM(r3, scur + 3, g3)
            GPREPM(r4, scur + 4, g4) GPREPM(r5, scur + 5, g5)
            GPREPM(r6, scur + 6, g6) GPREPM(r7, scur + 7, g7)
            STEPP(g0); STEPP(g1); STEPP(g2); STEPP(g3);
            STEPP(g4); STEPP(g5); STEPP(g6); STEPP(g7);
            scur += 8;
            r0 = n0; r1 = n1; r2 = n2; r3 = n3;
            r4 = n4; r5 = n5; r6 = n6; r7 = n7;
        }
        {   // epilogue: 7 steps (role 0) or 8 steps (roles 1/3)
            float g0, g1, g2, g3, g4, g5, g6;
            GPREPM(r0, scur + 0, g0) GPREPM(r1, scur + 1, g1)
            GPREPM(r2, scur + 2, g2) GPREPM(r3, scur + 3, g3)
            GPREPM(r4, scur + 4, g4) GPREPM(r5, scur + 5, g5)
            GPREPM(r6, scur + 6, g6)
            STEPP(g0); STEPP(g1); STEPP(g2); STEPP(g3);
            STEPP(g4); STEPP(g5); STEPP(g6);
            if (role != 0) {
                float g7x;
                GPREPM(r7, scur + 7, g7x)
                STEPP(g7x);
            }
        }
    } else {
        // roles 2/4/5: bwd, rows sHi..sHi-127 (128 E-applications)
        const int sHi = (role == 2) ? 255 : ((role == 4) ? 383 : 511);
        float q;
        if (role == 5) {
            float u0 = trans[65 * TSTRIDE + j];           // stop vector
            anchor = first_lane(u0) + 4.0f;
            q = __expf(u0 - anchor);
        } else {
            anchor = 0.0f;
            q = 1.0f;                                     // uniform start
        }
        float r0 = em[(size_t)(sHi - 0) * TT + j], r1 = em[(size_t)(sHi - 1) * TT + j];
        float r2 = em[(size_t)(sHi - 2) * TT + j], r3 = em[(size_t)(sHi - 3) * TT + j];
        float r4 = em[(size_t)(sHi - 4) * TT + j], r5 = em[(size_t)(sHi - 5) * TT + j];
        float r6 = em[(size_t)(sHi - 6) * TT + j], r7 = em[(size_t)(sHi - 7) * TT + j];
        const float* pe = em + (size_t)(sHi - 8) * TT + j;
        int scur = sHi;
        {   // init: fold diag at row sHi
            float h0i;
            GPREPM(r0, sHi, h0i)
            t = q * h0i;
        }
        for (int it = 0; it < 15; ++it) {       // 120 steps
            float n0 = pe[0],    n1 = pe[-64],  n2 = pe[-128], n3 = pe[-192];
            float n4 = pe[-256], n5 = pe[-320], n6 = pe[-384], n7 = pe[-448];
            pe -= 512;
            float g1, g2, g3, g4, g5, g6, g7, g8;
            GPREPM(r1, scur - 1, g1) GPREPM(r2, scur - 2, g2)
            GPREPM(r3, scur - 3, g3) GPREPM(r4, scur - 4, g4)
            GPREPM(r5, scur - 5, g5) GPREPM(r6, scur - 6, g6)
            GPREPM(r7, scur - 7, g7) GPREPM(n0, scur - 8, g8)
            STEPP(g1); STEPP(g2); STEPP(g3); STEPP(g4);
            STEPP(g5); STEPP(g6); STEPP(g7); STEPP(g8);
            scur -= 8;
            r0 = n0; r1 = n1; r2 = n2; r3 = n3;
            r4 = n4; r5 = n5; r6 = n6; r7 = n7;
        }
        {   // epilogue: rows scur-1..scur-7 then final E with g=1
            float g1, g2, g3, g4, g5, g6, g7;
            GPREPM(r1, scur - 1, g1) GPREPM(r2, scur - 2, g2)
            GPREPM(r3, scur - 3, g3) GPREPM(r4, scur - 4, g4)
            GPREPM(r5, scur - 5, g5) GPREPM(r6, scur - 6, g6)
            GPREPM(r7, scur - 7, g7)
            STEPP(g1); STEPP(g2); STEPP(g3); STEPP(g4);
            STEPP(g5); STEPP(g6); STEPP(g7); STEPP(1.0f);
        }
    }
#undef STEPP
#undef GPREPM
#undef XCH32F
#undef XCH16F

    ws_state[(size_t)b * 384 + role * 64 + j] = anchor + Lc + L2 * LN2 + __logf(t);
}

// Per-batch wave: rank-1 composition + gold path.
// logZ = LSE(d+Cu) + LSE(CTu+Bu) + LSE(BTu+a) - LSE(Cu) - LSE(Bu)
__global__ __launch_bounds__(64) void crf_combine_kernel(
    const float* __restrict__ emissions,
    const int*   __restrict__ tags,
    const float* __restrict__ mask,
    const float* __restrict__ trans,
    const float* __restrict__ ws_state,
    float* __restrict__ diff_out)
{
    const int b = blockIdx.x;
    const int j = threadIdx.x;
    const float* em = emissions + (size_t)b * SS * TT;
    const float* mk = mask + (size_t)b * SS;
    const float* W = ws_state + (size_t)b * 384;

    const float la  = W[0 * 64 + j];   // A-fwd  (exact)
    const float lBu = W[1 * 64 + j];   // B fwd-from-ones
    const float lBT = W[2 * 64 + j];   // B bwd-from-ones
    const float lCu = W[3 * 64 + j];   // C fwd-from-ones
    const float lCT = W[4 * 64 + j];   // C bwd-from-ones
    const float ld  = W[5 * 64 + j];   // D-bwd  (exact)

#define WLSE(X, OUT) { float x_ = (X); float m_ = x_; \
        _Pragma("unroll") \
        for (int off = 32; off; off >>= 1) m_ = fmaxf(m_, __shfl_xor(m_, off)); \
        float e_ = __expf(x_ - m_); \
        _Pragma("unroll") \
        for (int off = 32; off; off >>= 1) e_ += __shfl_xor(e_, off); \
        OUT = m_ + __logf(e_); }

    float z1, z2, z3, z4, z5;
    WLSE(ld + lCu, z1)
    WLSE(lCT + lBu, z2)
    WLSE(lBT + la, z3)
    WLSE(lCu, z4)
    WLSE(lBu, z5)
#undef WLSE
    const float zres = z1 + z2 + z3 - z4 - z5;

    float msum = 0.f;
    #pragma unroll
    for (int t = 0; t < 8; ++t) msum += mk[j + 64 * t];
    #pragma unroll
    for (int off = 32; off; off >>= 1) msum += __shfl_xor(msum, off);
    const int len = (int)(first_lane(msum) + 0.5f);

    const int* tg = tags + (size_t)b * SS;
    float acc = 0.f;
    for (int s = j; s < SS; s += 64) {
        if (s < len) {
            if (s > 0) {
                int curr = tg[s], prev = tg[s - 1];
                acc += trans[curr * TSTRIDE + prev] + em[s * TT + curr];
            } else {
                int t0_ = tg[0];
                acc += em[t0_] + trans[t0_ * TSTRIDE + TT];
            }
        }
    }
    #pragma unroll
    for (int off = 32; off; off >>= 1) acc += __shfl_xor(acc, off);
    if (j == 0) {
        int last = tg[len - 1];
        acc += trans[65 * TSTRIDE + last];
        diff_out[b] = zres - acc;
    }
}

__global__ __launch_bounds__(256) void crf_final_kernel(
    const float* __restrict__ diff,
    float* __restrict__ out)
{
    __shared__ float sdata[4];
    int t = threadIdx.x;
    float v = 0.f;
    for (int i = t; i < BB; i += 256) v += diff[i];
    #pragma unroll
    for (int off = 32; off; off >>= 1) v += __shfl_xor(v, off);
    if ((t & 63) == 0) sdata[t >> 6] = v;
    __syncthreads();
    if (t == 0) out[0] = (sdata[0] + sdata[1] + sdata[2] + sdata[3]) * (1.0f / BB);
}

extern "C" void kernel_launch(void* const* d_in, const int* in_sizes, int n_in,
                              void* d_out, int out_size, void* d_ws, size_t ws_size,
                              hipStream_t stream) {
    const float* emissions = (const float*)d_in[0];
    const int*   tags      = (const int*)d_in[1];
    const float* mask      = (const float*)d_in[2];
    const float* trans     = (const float*)d_in[3];
    float* out  = (float*)d_out;
    float* ws_state = (float*)d_ws;             // 512*384 floats
    float* diff = ws_state + (size_t)BB * 384;  // 512 floats

    crf_scan6_kernel<<<6 * BB, 64, 0, stream>>>(emissions, mask, trans, ws_state);
    crf_combine_kernel<<<BB, 64, 0, stream>>>(emissions, tags, mask, trans,
                                              ws_state, diff);
    crf_final_kernel<<<1, 256, 0, stream>>>(diff, out);
}

// Round 21
// 78.643 us; speedup vs baseline: 1.0314x; 1.0314x over previous
//
#include <hip/hip_runtime.h>

#define BB 512
#define SS 512
#define TT 64
#define TSTRIDE 66   // transitions is (66,66)

typedef _Float16 h2 __attribute__((ext_vector_type(2)));
typedef int i2v __attribute__((ext_vector_type(2)));

static __device__ __forceinline__ float first_lane(float v) {
    return __int_as_float(__builtin_amdgcn_readfirstlane(__float_as_int(v)));
}
static __device__ __forceinline__ unsigned pk_f16(float a, float b) {
    return __builtin_bit_cast(unsigned, __builtin_amdgcn_cvt_pkrtz(a, b));
}
static __device__ __forceinline__ h2 as_h2(unsigned u) {
    return __builtin_bit_cast(h2, u);
}
static __device__ __forceinline__ unsigned bperm(int addr, unsigned v) {
    return (unsigned)__builtin_amdgcn_ds_bpermute(addr, (int)v);
}
static __device__ __forceinline__ float swz16f(float v) {   // value from lane^16
    return __int_as_float(__builtin_amdgcn_ds_swizzle(__float_as_int(v), 0x401F));
}
#define FDOT2(a, b, c) __builtin_amdgcn_fdot2((a), (b), (c), false)
#define DPPF(v, ctrl) __int_as_float(__builtin_amdgcn_mov_dpp(__float_as_int(v), (ctrl), 0xF, 0xF, true))
#define DPPU(v, ctrl) ((unsigned)__builtin_amdgcn_mov_dpp((int)(v), (ctrl), 0xF, 0xF, true))

#define DO32(F) F(0) F(1) F(2) F(3) F(4) F(5) F(6) F(7) \
                F(8) F(9) F(10) F(11) F(12) F(13) F(14) F(15) \
                F(16) F(17) F(18) F(19) F(20) F(21) F(22) F(23) \
                F(24) F(25) F(26) F(27) F(28) F(29) F(30) F(31)

// R21: rank-1 4-segment MITM (absmax-0 verified, R16) restructured as
// TRIPLE-CHAIN waves at waves_per_eu(1,1) — the only config where the
// E-table provably stays register-resident (R16-R20: any max>1 remats LDS
// loads into the loop, VGPR 68, ~77us). One wave runs the 3 SAME-direction
// chains sharing ONE 32-reg E-table; 1024 waves = 1/SIMD exactly. In-wave
// chain interleaving fills dependent-latency bubbles (R14-proven: 477
// cy/step-pair vs 596 solo) -> issue-bound ~840 cy per 3-chain round.
// fwd wave (dir=0): a = steps 1..127 from v0 (role0); Bu = 128..255 from
// ones (role1); Cu = 256..383 from ones, masked (role3).
// bwd wave (dir=1): BTu = rows 255..128 from ones (role2); CTu = 383..256
// masked (role4); d = 511..384 from stop, masked (role5).
// logZ = LSE(d+Cu)+LSE(CTu+Bu)+LSE(BTu+a)-LSE(Cu)-LSE(Bu).
// Step = R15 skeleton: product-form recurrence, blocked dots
// (tl={0,2,7,5,15,13,8,10}), VALU reduce (perm16+perm32).
__global__ __launch_bounds__(64)
__attribute__((amdgpu_waves_per_eu(1, 1)))
void crf_scan_tri_kernel(
    const float* __restrict__ emissions,   // [B,S,T]
    const float* __restrict__ mask,        // [B,S]
    const float* __restrict__ trans,       // [66,66]
    float* __restrict__ ws_state)          // [B][6][64] log-form vectors
{
    __shared__ unsigned EQ[32][64];        // 8 KB E-fragment staging

    const int blk = blockIdx.x;
    const int b   = blk >> 1;
    const int dir = blk & 1;
    const int j   = threadIdx.x;   // 0..63
    const bool lo32  = (j < 32);
    const bool odd16 = (j & 16) != 0;
    const int a32v = ((j ^ 32) << 2);      // bpermute fallback address

    const float* em = emissions + (size_t)b * SS * TT;
    const float* mk = mask + (size_t)b * SS;

    // ---- E fragments, pre-permuted (R11-verified layout) ----
    {
        const int tl[8] = {0, 2, 7, 5, 15, 13, 8, 10};
        #pragma unroll
        for (int w = 0; w < 32; ++w) {
            int m = w >> 3, k = w & 7;
            int y0 = j ^ tl[k];
            int y1 = y0 ^ 1;
            int x  = j ^ (m << 4);
            if (dir == 0)   // fwd: M[x][y] = trans[y*66 + x]
                EQ[w][j] = pk_f16(__expf(trans[y0 * TSTRIDE + x]),
                                  __expf(trans[y1 * TSTRIDE + x]));
            else            // bwd: M[x][y] = trans[x*66 + y]
                EQ[w][j] = pk_f16(__expf(trans[x * TSTRIDE + y0]),
                                  __expf(trans[x * TSTRIDE + y1]));
        }
    }
    __syncthreads();

#define CDECL(K) const unsigned c##K = EQ[K][j];
    DO32(CDECL)
#undef CDECL

#if defined(__has_builtin) && __has_builtin(__builtin_amdgcn_permlane32_swap)
#define XCH32F(DST, SRC) { i2v r_ = __builtin_amdgcn_permlane32_swap( \
                               __float_as_int(SRC), __float_as_int(SRC), false, false); \
                           DST = __int_as_float(lo32 ? r_.y : r_.x); }
#else
#define XCH32F(DST, SRC) { DST = __int_as_float((int)bperm(a32v, (unsigned)__float_as_int(SRC))); }
#endif

#if defined(__has_builtin) && __has_builtin(__builtin_amdgcn_permlane16_swap)
#define XCH16F(DST, SRC) { i2v r_ = __builtin_amdgcn_permlane16_swap( \
                               __float_as_int(SRC), __float_as_int(SRC), false, false); \
                           DST = __int_as_float(odd16 ? r_.x : r_.y); }
#else
#define XCH16F(DST, SRC) { DST = swz16f(SRC); }
#endif

    // len (len in [256,512])
    float msum = 0.f;
    #pragma unroll
    for (int tq = 0; tq < 8; ++tq) msum += mk[j + 64 * tq];
    #pragma unroll
    for (int off = 32; off; off >>= 1) msum += __shfl_xor(msum, off);
    const int len = (int)(first_lane(msum) + 0.5f);

    const float LN2 = 0.69314718055994531f;

    // one E-application in product form on state T (side chain L2V)
#define SP(T, L2V, GK) do { \
        float pn_ = DPPF(T, 0xB1); \
        unsigned W0 = pk_f16(T, pn_); \
        unsigned W1 = DPPU(W0, 0x4E); \
        unsigned W2 = DPPU(W0, 0x141); \
        unsigned W3 = DPPU(W1, 0x141); \
        unsigned W4 = DPPU(W0, 0x140); \
        unsigned W5 = DPPU(W1, 0x140); \
        unsigned W6 = DPPU(W4, 0x141); \
        unsigned W7 = DPPU(W5, 0x141); \
        float a0_ = 0.f, a1_ = 0.f, a2_ = 0.f, a3_ = 0.f; \
        a0_ = FDOT2(as_h2(W0), as_h2(c0),  a0_); \
        a1_ = FDOT2(as_h2(W0), as_h2(c8),  a1_); \
        a2_ = FDOT2(as_h2(W0), as_h2(c16), a2_); \
        a3_ = FDOT2(as_h2(W0), as_h2(c24), a3_); \
        a0_ = FDOT2(as_h2(W1), as_h2(c1),  a0_); \
        a1_ = FDOT2(as_h2(W1), as_h2(c9),  a1_); \
        a2_ = FDOT2(as_h2(W1), as_h2(c17), a2_); \
        a3_ = FDOT2(as_h2(W1), as_h2(c25), a3_); \
        a0_ = FDOT2(as_h2(W2), as_h2(c2),  a0_); \
        a1_ = FDOT2(as_h2(W2), as_h2(c10), a1_); \
        a2_ = FDOT2(as_h2(W2), as_h2(c18), a2_); \
        a3_ = FDOT2(as_h2(W2), as_h2(c26), a3_); \
        a0_ = FDOT2(as_h2(W3), as_h2(c3),  a0_); \
        a1_ = FDOT2(as_h2(W3), as_h2(c11), a1_); \
        a2_ = FDOT2(as_h2(W3), as_h2(c19), a2_); \
        a3_ = FDOT2(as_h2(W3), as_h2(c27), a3_); \
        a0_ = FDOT2(as_h2(W4), as_h2(c4),  a0_); \
        a1_ = FDOT2(as_h2(W4), as_h2(c12), a1_); \
        a2_ = FDOT2(as_h2(W4), as_h2(c20), a2_); \
        a3_ = FDOT2(as_h2(W4), as_h2(c28), a3_); \
        a0_ = FDOT2(as_h2(W5), as_h2(c5),  a0_); \
        a1_ = FDOT2(as_h2(W5), as_h2(c13), a1_); \
        a2_ = FDOT2(as_h2(W5), as_h2(c21), a2_); \
        a3_ = FDOT2(as_h2(W5), as_h2(c29), a3_); \
        a0_ = FDOT2(as_h2(W6), as_h2(c6),  a0_); \
        a1_ = FDOT2(as_h2(W6), as_h2(c14), a1_); \
        a2_ = FDOT2(as_h2(W6), as_h2(c22), a2_); \
        a3_ = FDOT2(as_h2(W6), as_h2(c30), a3_); \
        a0_ = FDOT2(as_h2(W7), as_h2(c7),  a0_); \
        a1_ = FDOT2(as_h2(W7), as_h2(c15), a1_); \
        a2_ = FDOT2(as_h2(W7), as_h2(c23), a2_); \
        a3_ = FDOT2(as_h2(W7), as_h2(c31), a3_); \
        float a1x_, a3x_; \
        XCH16F(a1x_, a1_) \
        XCH16F(a3x_, a3_) \
        float V0 = a0_ + a1x_; \
        float V1 = a2_ + a3x_; \
        float Vx; XCH32F(Vx, V1); \
        float sum_ = V0 + Vx; \
        float s0_ = first_lane(sum_); \
        L2V += __log2f(s0_); \
        T = (sum_ * (GK)) * __builtin_amdgcn_rcpf(s0_); \
    } while (0)

#define GPF(RK, GOUT, LCV) { float e0_ = first_lane(RK); \
                             GOUT = __expf((RK) - e0_ - 4.0f); LCV += e0_ + 4.0f; }
#define GPM(RK, SV, GOUT, LCV) { float ee_ = ((SV) < len) ? (RK) : 0.0f; \
                                 float e0_ = first_lane(ee_); \
                                 GOUT = __expf(ee_ - e0_ - 4.0f); LCV += e0_ + 4.0f; }

    if (dir == 0) {
        // ===== fwd wave: a (1..127, v0), Bu (128..255), Cu (256..383 msk) ==
        float sc0 = em[j] + trans[j * TSTRIDE + TT];   // mask[0]==1 always
        const float anchA = first_lane(sc0) + 4.0f;
        float tA = __expf(sc0 - anchA);
        float tB = 1.0f, tC = 1.0f;
        float L2A = 0.f, LcA = 0.f, L2B = 0.f, LcB = 0.f, L2C = 0.f, LcC = 0.f;

        float rA0 = em[1*TT+j], rA1 = em[2*TT+j], rA2 = em[3*TT+j], rA3 = em[4*TT+j];
        float rA4 = em[5*TT+j], rA5 = em[6*TT+j], rA6 = em[7*TT+j], rA7 = em[8*TT+j];
        float rB0 = em[128*TT+j], rB1 = em[129*TT+j], rB2 = em[130*TT+j], rB3 = em[131*TT+j];
        float rB4 = em[132*TT+j], rB5 = em[133*TT+j], rB6 = em[134*TT+j], rB7 = em[135*TT+j];
        float rC0 = em[256*TT+j], rC1 = em[257*TT+j], rC2 = em[258*TT+j], rC3 = em[259*TT+j];
        float rC4 = em[260*TT+j], rC5 = em[261*TT+j], rC6 = em[262*TT+j], rC7 = em[263*TT+j];
        const float* peA = em + 9 * TT + j;
        const float* peB = em + 136 * TT + j;
        const float* peC = em + 264 * TT + j;
        int svC = 256;

#define TRIF(K) { float g_; \
        GPF(rA##K, g_, LcA) SP(tA, L2A, g_); \
        GPF(rB##K, g_, LcB) SP(tB, L2B, g_); \
        GPM(rC##K, svC + K, g_, LcC) SP(tC, L2C, g_); }

        for (int it = 0; it < 15; ++it) {   // 120 steps per chain
            float nA0 = peA[0],   nA1 = peA[64],  nA2 = peA[128], nA3 = peA[192];
            float nA4 = peA[256], nA5 = peA[320], nA6 = peA[384], nA7 = peA[448];
            float nB0 = peB[0],   nB1 = peB[64],  nB2 = peB[128], nB3 = peB[192];
            float nB4 = peB[256], nB5 = peB[320], nB6 = peB[384], nB7 = peB[448];
            float nC0 = peC[0],   nC1 = peC[64],  nC2 = peC[128], nC3 = peC[192];
            float nC4 = peC[256], nC5 = peC[320], nC6 = peC[384], nC7 = peC[448];
            peA += 512; peB += 512; peC += 512;
            TRIF(0) TRIF(1) TRIF(2) TRIF(3)
            TRIF(4) TRIF(5) TRIF(6) TRIF(7)
            svC += 8;
            rA0 = nA0; rA1 = nA1; rA2 = nA2; rA3 = nA3;
            rA4 = nA4; rA5 = nA5; rA6 = nA6; rA7 = nA7;
            rB0 = nB0; rB1 = nB1; rB2 = nB2; rB3 = nB3;
            rB4 = nB4; rB5 = nB5; rB6 = nB6; rB7 = nB7;
            rC0 = nC0; rC1 = nC1; rC2 = nC2; rC3 = nC3;
            rC4 = nC4; rC5 = nC5; rC6 = nC6; rC7 = nC7;
        }
#undef TRIF
        {   // epilogue: A rows 121..127 (7), B rows 248..255 (8), C 376..383 (8)
            float g_;
            GPF(rA0, g_, LcA) SP(tA, L2A, g_);
            GPF(rA1, g_, LcA) SP(tA, L2A, g_);
            GPF(rA2, g_, LcA) SP(tA, L2A, g_);
            GPF(rA3, g_, LcA) SP(tA, L2A, g_);
            GPF(rA4, g_, LcA) SP(tA, L2A, g_);
            GPF(rA5, g_, LcA) SP(tA, L2A, g_);
            GPF(rA6, g_, LcA) SP(tA, L2A, g_);
            GPF(rB0, g_, LcB) SP(tB, L2B, g_);
            GPF(rB1, g_, LcB) SP(tB, L2B, g_);
            GPF(rB2, g_, LcB) SP(tB, L2B, g_);
            GPF(rB3, g_, LcB) SP(tB, L2B, g_);
            GPF(rB4, g_, LcB) SP(tB, L2B, g_);
            GPF(rB5, g_, LcB) SP(tB, L2B, g_);
            GPF(rB6, g_, LcB) SP(tB, L2B, g_);
            GPF(rB7, g_, LcB) SP(tB, L2B, g_);
            GPM(rC0, svC + 0, g_, LcC) SP(tC, L2C, g_);
            GPM(rC1, svC + 1, g_, LcC) SP(tC, L2C, g_);
            GPM(rC2, svC + 2, g_, LcC) SP(tC, L2C, g_);
            GPM(rC3, svC + 3, g_, LcC) SP(tC, L2C, g_);
            GPM(rC4, svC + 4, g_, LcC) SP(tC, L2C, g_);
            GPM(rC5, svC + 5, g_, LcC) SP(tC, L2C, g_);
            GPM(rC6, svC + 6, g_, LcC) SP(tC, L2C, g_);
            GPM(rC7, svC + 7, g_, LcC) SP(tC, L2C, g_);
        }
        ws_state[(size_t)b * 384 + 0 * 64 + j] = anchA + LcA + L2A * LN2 + __logf(tA);
        ws_state[(size_t)b * 384 + 1 * 64 + j] = LcB + L2B * LN2 + __logf(tB);
        ws_state[(size_t)b * 384 + 3 * 64 + j] = LcC + L2C * LN2 + __logf(tC);
    } else {
        // ===== bwd wave: BTu (255..128), CTu (383..256 msk), d (511..384) ==
        float u0 = trans[65 * TSTRIDE + j];            // stop vector
        const float anchF = first_lane(u0) + 4.0f;
        float qF = __expf(u0 - anchF);
        float tD, tE, tF;
        float L2D = 0.f, LcD = 0.f, L2E = 0.f, LcE = 0.f, L2F = 0.f, LcF = 0.f;

        float rD0 = em[255*TT+j], rD1 = em[254*TT+j], rD2 = em[253*TT+j], rD3 = em[252*TT+j];
        float rD4 = em[251*TT+j], rD5 = em[250*TT+j], rD6 = em[249*TT+j], rD7 = em[248*TT+j];
        float rE0 = em[383*TT+j], rE1 = em[382*TT+j], rE2 = em[381*TT+j], rE3 = em[380*TT+j];
        float rE4 = em[379*TT+j], rE5 = em[378*TT+j], rE6 = em[377*TT+j], rE7 = em[376*TT+j];
        float rF0 = em[511*TT+j], rF1 = em[510*TT+j], rF2 = em[509*TT+j], rF3 = em[508*TT+j];
        float rF4 = em[507*TT+j], rF5 = em[506*TT+j], rF6 = em[505*TT+j], rF7 = em[504*TT+j];
        const float* peD = em + 247 * TT + j;
        const float* peE = em + 375 * TT + j;
        const float* peF = em + 503 * TT + j;
        int svE = 383, svF = 511;

        {   // init: fold diag at top rows
            float g_;
            GPF(rD0, g_, LcD)           tD = g_;            // row 255 < 256 <= len
            GPM(rE0, 383, g_, LcE)      tE = g_;
            GPM(rF0, 511, g_, LcF)      tF = qF * g_;
        }

#define TRIB(KD, KE, KF, OE, OF) { float g_; \
        GPF(KD, g_, LcD) SP(tD, L2D, g_); \
        GPM(KE, svE - (OE), g_, LcE) SP(tE, L2E, g_); \
        GPM(KF, svF - (OF), g_, LcF) SP(tF, L2F, g_); }

        for (int it = 0; it < 15; ++it) {   // 120 steps per chain
            float nD0 = peD[0],    nD1 = peD[-64],  nD2 = peD[-128], nD3 = peD[-192];
            float nD4 = peD[-256], nD5 = peD[-320], nD6 = peD[-384], nD7 = peD[-448];
            float nE0 = peE[0],    nE1 = peE[-64],  nE2 = peE[-128], nE3 = peE[-192];
            float nE4 = peE[-256], nE5 = peE[-320], nE6 = peE[-384], nE7 = peE[-448];
            float nF0 = peF[0],    nF1 = peF[-64],  nF2 = peF[-128], nF3 = peF[-192];
            float nF4 = peF[-256], nF5 = peF[-320], nF6 = peF[-384], nF7 = peF[-448];
            peD -= 512; peE -= 512; peF -= 512;
            TRIB(rD1, rE1, rF1, 1, 1)
            TRIB(rD2, rE2, rF2, 2, 2)
            TRIB(rD3, rE3, rF3, 3, 3)
            TRIB(rD4, rE4, rF4, 4, 4)
            TRIB(rD5, rE5, rF5, 5, 5)
            TRIB(rD6, rE6, rF6, 6, 6)
            TRIB(rD7, rE7, rF7, 7, 7)
            TRIB(nD0, nE0, nF0, 8, 8)
            svE -= 8; svF -= 8;
            rD0 = nD0; rD1 = nD1; rD2 = nD2; rD3 = nD3;
            rD4 = nD4; rD5 = nD5; rD6 = nD6; rD7 = nD7;
            rE0 = nE0; rE1 = nE1; rE2 = nE2; rE3 = nE3;
            rE4 = nE4; rE5 = nE5; rE6 = nE6; rE7 = nE7;
            rF0 = nF0; rF1 = nF1; rF2 = nF2; rF3 = nF3;
            rF4 = nF4; rF5 = nF5; rF6 = nF6; rF7 = nF7;
        }
        // epilogue: D rows 134..128 (7 g-steps), E 262..256, F 390..384,
        // then one final E-application with g=1 per chain.
        TRIB(rD1, rE1, rF1, 1, 1)
        TRIB(rD2, rE2, rF2, 2, 2)
        TRIB(rD3, rE3, rF3, 3, 3)
        TRIB(rD4, rE4, rF4, 4, 4)
        TRIB(rD5, rE5, rF5, 5, 5)
        TRIB(rD6, rE6, rF6, 6, 6)
        TRIB(rD7, rE7, rF7, 7, 7)
#undef TRIB
        SP(tD, L2D, 1.0f);
        SP(tE, L2E, 1.0f);
        SP(tF, L2F, 1.0f);

        ws_state[(size_t)b * 384 + 2 * 64 + j] = LcD + L2D * LN2 + __logf(tD);
        ws_state[(size_t)b * 384 + 4 * 64 + j] = LcE + L2E * LN2 + __logf(tE);
        ws_state[(size_t)b * 384 + 5 * 64 + j] = anchF + LcF + L2F * LN2 + __logf(tF);
    }
#undef SP
#undef GPF
#undef GPM
#undef XCH32F
#undef XCH16F
}

// Per-batch wave: rank-1 composition + gold path (verified R16).
// logZ = LSE(d+Cu) + LSE(CTu+Bu) + LSE(BTu+a) - LSE(Cu) - LSE(Bu)
__global__ __launch_bounds__(64) void crf_combine_kernel(
    const float* __restrict__ emissions,
    const int*   __restrict__ tags,
    const float* __restrict__ mask,
    const float* __restrict__ trans,
    const float* __restrict__ ws_state,
    float* __restrict__ diff_out)
{
    const int b = blockIdx.x;
    const int j = threadIdx.x;
    const float* em = emissions + (size_t)b * SS * TT;
    const float* mk = mask + (size_t)b * SS;
    const float* W = ws_state + (size_t)b * 384;

    const float la  = W[0 * 64 + j];   // A-fwd  (exact)
    const float lBu = W[1 * 64 + j];   // B fwd-from-ones
    const float lBT = W[2 * 64 + j];   // B bwd-from-ones
    const float lCu = W[3 * 64 + j];   // C fwd-from-ones
    const float lCT = W[4 * 64 + j];   // C bwd-from-ones
    const float ld  = W[5 * 64 + j];   // D-bwd  (exact)

#define WLSE(X, OUT) { float x_ = (X); float m_ = x_; \
        _Pragma("unroll") \
        for (int off = 32; off; off >>= 1) m_ = fmaxf(m_, __shfl_xor(m_, off)); \
        float e_ = __expf(x_ - m_); \
        _Pragma("unroll") \
        for (int off = 32; off; off >>= 1) e_ += __shfl_xor(e_, off); \
        OUT = m_ + __logf(e_); }

    float z1, z2, z3, z4, z5;
    WLSE(ld + lCu, z1)
    WLSE(lCT + lBu, z2)
    WLSE(lBT + la, z3)
    WLSE(lCu, z4)
    WLSE(lBu, z5)
#undef WLSE
    const float zres = z1 + z2 + z3 - z4 - z5;

    float msum = 0.f;
    #pragma unroll
    for (int t = 0; t < 8; ++t) msum += mk[j + 64 * t];
    #pragma unroll
    for (int off = 32; off; off >>= 1) msum += __shfl_xor(msum, off);
    const int len = (int)(first_lane(msum) + 0.5f);

    const int* tg = tags + (size_t)b * SS;
    float acc = 0.f;
    for (int s = j; s < SS; s += 64) {
        if (s < len) {
            if (s > 0) {
                int curr = tg[s], prev = tg[s - 1];
                acc += trans[curr * TSTRIDE + prev] + em[s * TT + curr];
            } else {
                int t0_ = tg[0];
                acc += em[t0_] + trans[t0_ * TSTRIDE + TT];
            }
        }
    }
    #pragma unroll
    for (int off = 32; off; off >>= 1) acc += __shfl_xor(acc, off);
    if (j == 0) {
        int last = tg[len - 1];
        acc += trans[65 * TSTRIDE + last];
        diff_out[b] = zres - acc;
    }
}

__global__ __launch_bounds__(256) void crf_final_kernel(
    const float* __restrict__ diff,
    float* __restrict__ out)
{
    __shared__ float sdata[4];
    int t = threadIdx.x;
    float v = 0.f;
    for (int i = t; i < BB; i += 256) v += diff[i];
    #pragma unroll
    for (int off = 32; off; off >>= 1) v += __shfl_xor(v, off);
    if ((t & 63) == 0) sdata[t >> 6] = v;
    __syncthreads();
    if (t == 0) out[0] = (sdata[0] + sdata[1] + sdata[2] + sdata[3]) * (1.0f / BB);
}

extern "C" void kernel_launch(void* const* d_in, const int* in_sizes, int n_in,
                              void* d_out, int out_size, void* d_ws, size_t ws_size,
                              hipStream_t stream) {
    const float* emissions = (const float*)d_in[0];
    const int*   tags      = (const int*)d_in[1];
    const float* mask      = (const float*)d_in[2];
    const float* trans     = (const float*)d_in[3];
    float* out  = (float*)d_out;
    float* ws_state = (float*)d_ws;             // 512*384 floats
    float* diff = ws_state + (size_t)BB * 384;  // 512 floats

    crf_scan_tri_kernel<<<2 * BB, 64, 0, stream>>>(emissions, mask, trans, ws_state);
    crf_combine_kernel<<<BB, 64, 0, stream>>>(emissions, tags, mask, trans,
                                              ws_state, diff);
    crf_final_kernel<<<1, 256, 0, stream>>>(diff, out);
}

// Round 22
// 62.097 us; speedup vs baseline: 1.3063x; 1.2664x over previous
//
#include <hip/hip_runtime.h>

#define BB 512
#define SS 512
#define TT 64
#define TSTRIDE 66   // transitions is (66,66)

typedef _Float16 h2 __attribute__((ext_vector_type(2)));
typedef int i2v __attribute__((ext_vector_type(2)));

static __device__ __forceinline__ float first_lane(float v) {
    return __int_as_float(__builtin_amdgcn_readfirstlane(__float_as_int(v)));
}
static __device__ __forceinline__ unsigned pk_f16(float a, float b) {
    return __builtin_bit_cast(unsigned, __builtin_amdgcn_cvt_pkrtz(a, b));
}
static __device__ __forceinline__ h2 as_h2(unsigned u) {
    return __builtin_bit_cast(h2, u);
}
static __device__ __forceinline__ unsigned bperm(int addr, unsigned v) {
    return (unsigned)__builtin_amdgcn_ds_bpermute(addr, (int)v);
}
static __device__ __forceinline__ float swz16f(float v) {   // value from lane^16
    return __int_as_float(__builtin_amdgcn_ds_swizzle(__float_as_int(v), 0x401F));
}
#define FDOT2(a, b, c) __builtin_amdgcn_fdot2((a), (b), (c), false)
#define DPPF(v, ctrl) __int_as_float(__builtin_amdgcn_mov_dpp(__float_as_int(v), (ctrl), 0xF, 0xF, true))
#define DPPU(v, ctrl) ((unsigned)__builtin_amdgcn_mov_dpp((int)(v), (ctrl), 0xF, 0xF, true))

#define DO32(F) F(0) F(1) F(2) F(3) F(4) F(5) F(6) F(7) \
                F(8) F(9) F(10) F(11) F(12) F(13) F(14) F(15) \
                F(16) F(17) F(18) F(19) F(20) F(21) F(22) F(23) \
                F(24) F(25) F(26) F(27) F(28) F(29) F(30) F(31)

// R22 = R15 verbatim (the best measured config: 61.8 us total).
// Cost model over R14-R21: wall = instances x cost(chains/wave);
// cost(1)=600, cost(2)=477, cost(3)=483 cy. MITM N=2,c=1 = 256x600 = 154K
// cy is the family optimum (rank-1 splits inflate instances faster than
// interleave reduces cost). E-table resident only at waves_per_eu(1,1).
// Step: product-form recurrence (exp/log off critical path), blocked dots
// (tl={0,2,7,5,15,13,8,10}, R11-verified), VALU reduce (perm16+perm32).
__global__ __launch_bounds__(64)
__attribute__((amdgpu_waves_per_eu(1, 1)))
void crf_scan2_kernel(
    const float* __restrict__ emissions,   // [B,S,T]
    const float* __restrict__ mask,        // [B,S]
    const float* __restrict__ trans,       // [66,66]
    float* __restrict__ ws_state)          // [B][128]: F[64] then U[64]
{
    __shared__ unsigned EQ[32][64];        // 8 KB E-fragment staging

    const int blk = blockIdx.x;
    const int b   = blk >> 1;
    const int dir = blk & 1;
    const int j   = threadIdx.x;   // 0..63
    const bool lo32  = (j < 32);
    const bool odd16 = (j & 16) != 0;
    const int a32v = ((j ^ 32) << 2);      // bpermute fallback address

    const float* em = emissions + (size_t)b * SS * TT;
    const float* mk = mask + (size_t)b * SS;

    // ---- E fragments, pre-permuted for the blocked scheme (R11 verified) --
    {
        const int tl[8] = {0, 2, 7, 5, 15, 13, 8, 10};
        #pragma unroll
        for (int w = 0; w < 32; ++w) {
            int m = w >> 3, k = w & 7;
            int y0 = j ^ tl[k];
            int y1 = y0 ^ 1;
            int x  = j ^ (m << 4);
            if (dir == 0)   // fwd: M[x][y] = trans[y*66 + x]
                EQ[w][j] = pk_f16(__expf(trans[y0 * TSTRIDE + x]),
                                  __expf(trans[y1 * TSTRIDE + x]));
            else            // bwd: M[x][y] = trans[x*66 + y]
                EQ[w][j] = pk_f16(__expf(trans[x * TSTRIDE + y0]),
                                  __expf(trans[x * TSTRIDE + y1]));
        }
    }
    __syncthreads();

#define CDECL(K) const unsigned c##K = EQ[K][j];
    DO32(CDECL)
#undef CDECL

#if defined(__has_builtin) && __has_builtin(__builtin_amdgcn_permlane32_swap)
#define XCH32F(DST, SRC) { i2v r_ = __builtin_amdgcn_permlane32_swap( \
                               __float_as_int(SRC), __float_as_int(SRC), false, false); \
                           DST = __int_as_float(lo32 ? r_.y : r_.x); }
#else
#define XCH32F(DST, SRC) { DST = __int_as_float((int)bperm(a32v, (unsigned)__float_as_int(SRC))); }
#endif

#if defined(__has_builtin) && __has_builtin(__builtin_amdgcn_permlane16_swap)
// odd-16-rows(vdst) <-> even-16-rows(src); with both = x: x[l^16] = odd16 ? .x : .y
#define XCH16F(DST, SRC) { i2v r_ = __builtin_amdgcn_permlane16_swap( \
                               __float_as_int(SRC), __float_as_int(SRC), false, false); \
                           DST = __int_as_float(odd16 ? r_.x : r_.y); }
#else
#define XCH16F(DST, SRC) { DST = swz16f(SRC); }
#endif

    float t, L2 = 0.f, Lc = 0.f;

#define STEPP(GK) do { \
        float pn_ = DPPF(t, 0xB1); \
        unsigned W0 = pk_f16(t, pn_); \
        unsigned W1 = DPPU(W0, 0x4E); \
        unsigned W2 = DPPU(W0, 0x141); \
        unsigned W3 = DPPU(W1, 0x141); \
        unsigned W4 = DPPU(W0, 0x140); \
        unsigned W5 = DPPU(W1, 0x140); \
        unsigned W6 = DPPU(W4, 0x141); \
        unsigned W7 = DPPU(W5, 0x141); \
        float a0_ = 0.f, a1_ = 0.f, a2_ = 0.f, a3_ = 0.f; \
        a0_ = FDOT2(as_h2(W0), as_h2(c0),  a0_); \
        a1_ = FDOT2(as_h2(W0), as_h2(c8),  a1_); \
        a2_ = FDOT2(as_h2(W0), as_h2(c16), a2_); \
        a3_ = FDOT2(as_h2(W0), as_h2(c24), a3_); \
        a0_ = FDOT2(as_h2(W1), as_h2(c1),  a0_); \
        a1_ = FDOT2(as_h2(W1), as_h2(c9),  a1_); \
        a2_ = FDOT2(as_h2(W1), as_h2(c17), a2_); \
        a3_ = FDOT2(as_h2(W1), as_h2(c25), a3_); \
        a0_ = FDOT2(as_h2(W2), as_h2(c2),  a0_); \
        a1_ = FDOT2(as_h2(W2), as_h2(c10), a1_); \
        a2_ = FDOT2(as_h2(W2), as_h2(c18), a2_); \
        a3_ = FDOT2(as_h2(W2), as_h2(c26), a3_); \
        a0_ = FDOT2(as_h2(W3), as_h2(c3),  a0_); \
        a1_ = FDOT2(as_h2(W3), as_h2(c11), a1_); \
        a2_ = FDOT2(as_h2(W3), as_h2(c19), a2_); \
        a3_ = FDOT2(as_h2(W3), as_h2(c27), a3_); \
        a0_ = FDOT2(as_h2(W4), as_h2(c4),  a0_); \
        a1_ = FDOT2(as_h2(W4), as_h2(c12), a1_); \
        a2_ = FDOT2(as_h2(W4), as_h2(c20), a2_); \
        a3_ = FDOT2(as_h2(W4), as_h2(c28), a3_); \
        a0_ = FDOT2(as_h2(W5), as_h2(c5),  a0_); \
        a1_ = FDOT2(as_h2(W5), as_h2(c13), a1_); \
        a2_ = FDOT2(as_h2(W5), as_h2(c21), a2_); \
        a3_ = FDOT2(as_h2(W5), as_h2(c29), a3_); \
        a0_ = FDOT2(as_h2(W6), as_h2(c6),  a0_); \
        a1_ = FDOT2(as_h2(W6), as_h2(c14), a1_); \
        a2_ = FDOT2(as_h2(W6), as_h2(c22), a2_); \
        a3_ = FDOT2(as_h2(W6), as_h2(c30), a3_); \
        a0_ = FDOT2(as_h2(W7), as_h2(c7),  a0_); \
        a1_ = FDOT2(as_h2(W7), as_h2(c15), a1_); \
        a2_ = FDOT2(as_h2(W7), as_h2(c23), a2_); \
        a3_ = FDOT2(as_h2(W7), as_h2(c31), a3_); \
        float a1x_, a3x_; \
        XCH16F(a1x_, a1_) \
        XCH16F(a3x_, a3_) \
        float V0 = a0_ + a1x_; \
        float V1 = a2_ + a3x_; \
        float Vx; XCH32F(Vx, V1); \
        float sum_ = V0 + Vx; \
        float s0_ = first_lane(sum_); \
        L2 += __log2f(s0_); \
        t = (sum_ * (GK)) * __builtin_amdgcn_rcpf(s0_); \
    } while (0)

#define GPREPF(RK, GOUT) { float e0_ = first_lane(RK); \
                           GOUT = __expf((RK) - e0_ - 4.0f); Lc += e0_ + 4.0f; }
#define GPREPB(RK, SV, GOUT) { float ee_ = ((SV) < len) ? (RK) : 0.0f; \
                               float e0_ = first_lane(ee_); \
                               GOUT = __expf(ee_ - e0_ - 4.0f); Lc += e0_ + 4.0f; }

    const float LN2 = 0.69314718055994531f;

    if (dir == 0) {
        // ---------- forward: steps 1..255 (unmasked; len >= 256) ----------
        float sc0 = em[j] + trans[j * TSTRIDE + TT];   // mask[0]==1 always
        const float m0c0 = first_lane(sc0) + 4.0f;
        t = __expf(sc0 - m0c0);

        float r0 = em[1 * TT + j], r1 = em[2 * TT + j];
        float r2 = em[3 * TT + j], r3 = em[4 * TT + j];
        float r4 = em[5 * TT + j], r5 = em[6 * TT + j];
        float r6 = em[7 * TT + j], r7 = em[8 * TT + j];
        const float* pe = em + 9 * TT + j;
        for (int it = 0; it < 31; ++it) {       // steps 1..248
            float n0 = pe[0],   n1 = pe[64],  n2 = pe[128], n3 = pe[192];
            float n4 = pe[256], n5 = pe[320], n6 = pe[384], n7 = pe[448];
            pe += 512;
            float g0, g1, g2, g3, g4, g5, g6, g7;
            GPREPF(r0, g0) GPREPF(r1, g1) GPREPF(r2, g2) GPREPF(r3, g3)
            GPREPF(r4, g4) GPREPF(r5, g5) GPREPF(r6, g6) GPREPF(r7, g7)
            STEPP(g0); STEPP(g1); STEPP(g2); STEPP(g3);
            STEPP(g4); STEPP(g5); STEPP(g6); STEPP(g7);
            r0 = n0; r1 = n1; r2 = n2; r3 = n3;
            r4 = n4; r5 = n5; r6 = n6; r7 = n7;
        }
        {   // steps 249..255 (7 steps, rings r0..r6)
            float g0, g1, g2, g3, g4, g5, g6;
            GPREPF(r0, g0) GPREPF(r1, g1) GPREPF(r2, g2) GPREPF(r3, g3)
            GPREPF(r4, g4) GPREPF(r5, g5) GPREPF(r6, g6)
            STEPP(g0); STEPP(g1); STEPP(g2); STEPP(g3);
            STEPP(g4); STEPP(g5); STEPP(g6);
        }
        ws_state[(size_t)b * 128 + j] = m0c0 + Lc + L2 * LN2 + __logf(t);
    } else {
        // ---------- backward: steps 511..256 ----------
        float msum = 0.f;
        #pragma unroll
        for (int tq = 0; tq < 8; ++tq) msum += mk[j + 64 * tq];
        #pragma unroll
        for (int off = 32; off; off >>= 1) msum += __shfl_xor(msum, off);
        const int len = (int)(first_lane(msum) + 0.5f);   // in [256,512]

        float u0 = trans[65 * TSTRIDE + j];               // u_511 = stop vector
        const float anc0 = first_lane(u0) + 4.0f;
        float q = __expf(u0 - anc0);

        float r0 = em[511 * TT + j], r1 = em[510 * TT + j];
        float r2 = em[509 * TT + j], r3 = em[508 * TT + j];
        float r4 = em[507 * TT + j], r5 = em[506 * TT + j];
        float r6 = em[505 * TT + j], r7 = em[504 * TT + j];
        const float* pe = em + 503 * TT + j;
        int scur = 511;

        // init: fold h@511 (STEP@p post-multiplies h@(p-1))
        {
            float h0i;
            GPREPB(r0, 511, h0i)
            t = q * h0i;
        }
        for (int it = 0; it < 31; ++it) {       // steps 511..264
            float n0 = pe[0],    n1 = pe[-64],  n2 = pe[-128], n3 = pe[-192];
            float n4 = pe[-256], n5 = pe[-320], n6 = pe[-384], n7 = pe[-448];
            pe -= 512;
            float g1, g2, g3, g4, g5, g6, g7, g8;
            GPREPB(r1, scur - 1, g1) GPREPB(r2, scur - 2, g2)
            GPREPB(r3, scur - 3, g3) GPREPB(r4, scur - 4, g4)
            GPREPB(r5, scur - 5, g5) GPREPB(r6, scur - 6, g6)
            GPREPB(r7, scur - 7, g7) GPREPB(n0, scur - 8, g8)
            STEPP(g1); STEPP(g2); STEPP(g3); STEPP(g4);
            STEPP(g5); STEPP(g6); STEPP(g7); STEPP(g8);
            scur -= 8;
            r0 = n0; r1 = n1; r2 = n2; r3 = n3;
            r4 = n4; r5 = n5; r6 = n6; r7 = n7;
        }
        {   // steps 263..256 (rings r0..r7 = rows 263..256)
            float g1, g2, g3, g4, g5, g6, g7;
            GPREPB(r1, 262, g1) GPREPB(r2, 261, g2) GPREPB(r3, 260, g3)
            GPREPB(r4, 259, g4) GPREPB(r5, 258, g5) GPREPB(r6, 257, g6)
            GPREPB(r7, 256, g7)
            STEPP(g1); STEPP(g2); STEPP(g3); STEPP(g4);
            STEPP(g5); STEPP(g6); STEPP(g7); STEPP(1.0f);
        }
        ws_state[(size_t)b * 128 + 64 + j] = anc0 + Lc + L2 * LN2 + __logf(t);
    }
#undef STEPP
#undef GPREPF
#undef GPREPB
#undef XCH32F
#undef XCH16F
}

// Per-batch wave: logZ = LSE_j(F[j]+U[j]), gold path, diff = logZ - gold.
__global__ __launch_bounds__(64) void crf_combine_kernel(
    const float* __restrict__ emissions,
    const int*   __restrict__ tags,
    const float* __restrict__ mask,
    const float* __restrict__ trans,
    const float* __restrict__ ws_state,
    float* __restrict__ diff_out)
{
    const int b = blockIdx.x;
    const int j = threadIdx.x;
    const float* em = emissions + (size_t)b * SS * TT;
    const float* mk = mask + (size_t)b * SS;

    float v = ws_state[(size_t)b * 128 + j] + ws_state[(size_t)b * 128 + 64 + j];
    float m = v;
    #pragma unroll
    for (int off = 32; off; off >>= 1) m = fmaxf(m, __shfl_xor(m, off));
    float e = __expf(v - m);
    #pragma unroll
    for (int off = 32; off; off >>= 1) e += __shfl_xor(e, off);
    float zres = m + __logf(e);

    float msum = 0.f;
    #pragma unroll
    for (int t = 0; t < 8; ++t) msum += mk[j + 64 * t];
    #pragma unroll
    for (int off = 32; off; off >>= 1) msum += __shfl_xor(msum, off);
    const int len = (int)(first_lane(msum) + 0.5f);

    const int* tg = tags + (size_t)b * SS;
    float acc = 0.f;
    for (int s = j; s < SS; s += 64) {
        if (s < len) {
            if (s > 0) {
                int curr = tg[s], prev = tg[s - 1];
                acc += trans[curr * TSTRIDE + prev] + em[s * TT + curr];
            } else {
                int t0_ = tg[0];
                acc += em[t0_] + trans[t0_ * TSTRIDE + TT];
            }
        }
    }
    #pragma unroll
    for (int off = 32; off; off >>= 1) acc += __shfl_xor(acc, off);
    if (j == 0) {
        int last = tg[len - 1];
        acc += trans[65 * TSTRIDE + last];
        diff_out[b] = zres - acc;
    }
}

__global__ __launch_bounds__(256) void crf_final_kernel(
    const float* __restrict__ diff,
    float* __restrict__ out)
{
    __shared__ float sdata[4];
    int t = threadIdx.x;
    float v = 0.f;
    for (int i = t; i < BB; i += 256) v += diff[i];
    #pragma unroll
    for (int off = 32; off; off >>= 1) v += __shfl_xor(v, off);
    if ((t & 63) == 0) sdata[t >> 6] = v;
    __syncthreads();
    if (t == 0) out[0] = (sdata[0] + sdata[1] + sdata[2] + sdata[3]) * (1.0f / BB);
}

extern "C" void kernel_launch(void* const* d_in, const int* in_sizes, int n_in,
                              void* d_out, int out_size, void* d_ws, size_t ws_size,
                              hipStream_t stream) {
    const float* emissions = (const float*)d_in[0];
    const int*   tags      = (const int*)d_in[1];
    const float* mask      = (const float*)d_in[2];
    const float* trans     = (const float*)d_in[3];
    float* out  = (float*)d_out;
    float* ws_state = (float*)d_ws;             // 512*128 floats
    float* diff = ws_state + (size_t)BB * 128;  // 512 floats

    crf_scan2_kernel<<<2 * BB, 64, 0, stream>>>(emissions, mask, trans, ws_state);
    crf_combine_kernel<<<BB, 64, 0, stream>>>(emissions, tags, mask, trans,
                                              ws_state, diff);
    crf_final_kernel<<<1, 256, 0, stream>>>(diff, out);
}